// Round 1
// baseline (79.783 us; speedup 1.0000x reference)
//
#include <hip/hip_runtime.h>

#define BATCH 64
#define NSAMP 1500
#define NFREQ 1251
#define NSEG  5
#define SEGLEN 300            // NSEG*SEGLEN == NSAMP, SEGLEN % 4 == 0
#define FBLK  256             // freqs per block
#define FCHUNKS 5             // 5*256 = 1280 >= 1251

// ---------------------------------------------------------------------------
// Kernel 1 (round 8): fused-segment Goertzel -> psd[b,f] directly.
// Grid (B, FCHUNKS) = 320 blocks x 256 threads. Each thread owns ONE freq and
// runs all 5 segment chains INTERLEAVED (5 independent (s1,s2) pairs -> 5-way
// ILP hides the 4-cyc fma dep chain even at ~1.25 waves/SIMD).
// Per-segment math, rotation, and the seg-order summation are bit-identical
// to the previous passing 2-stage version (which did the seg-sum in K2), so
// the final scalar is unchanged. Intermediate shrinks 3.2 MB float2 -> 320 KB
// float; K2's 25 strided gathers/thread become 5 coalesced loads.
//   s_k = x_k + 2cos(w) s_{k-1} - s_{k-2}
//   C_g = cos((M-1)w) s1 - cos(Mw) s2 ; S_g = sin((M-1)w) s1 - sin(Mw) s2
//   (C,S) += rot(seg-start phase) * (C_g,S_g), summed g = 0..4 in order.
// Trig in REVOLUTIONS (v_sin/v_cos). Thread (0,0,0) zeroes d_out for K2's
// atomicAdd (stream-ordered).
// ---------------------------------------------------------------------------
__global__ __launch_bounds__(256) void goertzel_psd_kernel(
    const float* __restrict__ x,          // [B,N]
    const float* __restrict__ fs,         // [B]
    const float* __restrict__ sampling_f, // [1]
    const float* __restrict__ f_range,    // f_min first
    float* __restrict__ psd,              // [B,NFREQ]
    float* __restrict__ out)              // [1] zeroed here
{
    __shared__ float4 xs4[NSAMP / 4];     // 375 float4 = 6 KB (whole signal)
    const int b   = blockIdx.x;
    const int tid = threadIdx.x;

    if (b == 0 && blockIdx.y == 0 && tid == 0) out[0] = 0.0f;

    const float4* xg = reinterpret_cast<const float4*>(x + b * NSAMP);
    for (int i = tid; i < NSAMP / 4; i += FBLK) xs4[i] = xg[i];
    __syncthreads();

    const int fidx = blockIdx.y * FBLK + tid;
    if (fidx >= NFREQ) return;

    // numpy arange fill semantics
    const float f_min = f_range[0];
    const float step  = sampling_f[0];
    const float delta = (f_min + step) - f_min;
    const float fv    = f_min + (float)fidx * delta;

    const float rho = fv / fs[b];                 // revolutions per sample
    float rf = rho - floorf(rho);
    const float coef = 2.0f * __builtin_amdgcn_cosf(rf);

    float s1[NSEG], s2[NSEG];
#pragma unroll
    for (int g = 0; g < NSEG; ++g) { s1[g] = 0.0f; s2[g] = 0.0f; }

#pragma unroll 3
    for (int k = 0; k < SEGLEN / 4; ++k) {
#pragma unroll
        for (int g = 0; g < NSEG; ++g) {
            float4 v = xs4[g * (SEGLEN / 4) + k];  // wave-uniform broadcast
            float t;
            t = fmaf(coef, s1[g], v.x - s2[g]); s2[g] = s1[g]; s1[g] = t;
            t = fmaf(coef, s1[g], v.y - s2[g]); s2[g] = s1[g]; s1[g] = t;
            t = fmaf(coef, s1[g], v.z - s2[g]); s2[g] = s1[g]; s1[g] = t;
            t = fmaf(coef, s1[g], v.w - s2[g]); s2[g] = s1[g]; s1[g] = t;
        }
    }

    // chain-end rotation terms: same M for every segment, compute once
    float aM  = (float)SEGLEN * rho;        aM  -= floorf(aM);
    float aM1 = (float)(SEGLEN - 1) * rho;  aM1 -= floorf(aM1);
    const float cM  = __builtin_amdgcn_cosf(aM);
    const float sM  = __builtin_amdgcn_sinf(aM);
    const float cM1 = __builtin_amdgcn_cosf(aM1);
    const float sM1 = __builtin_amdgcn_sinf(aM1);

    float C = 0.0f, S = 0.0f;
#pragma unroll
    for (int g = 0; g < NSEG; ++g) {
        float a0 = (float)(g * SEGLEN) * rho;  a0 -= floorf(a0);
        const float c0 = __builtin_amdgcn_cosf(a0);
        const float s0 = __builtin_amdgcn_sinf(a0);
        const float Cl = cM1 * s1[g] - cM * s2[g];
        const float Sl = sM1 * s1[g] - sM * s2[g];
        C += c0 * Cl - s0 * Sl;               // same add order as old K2 g-loop
        S += s0 * Cl + c0 * Sl;
    }

    psd[b * NFREQ + fidx] = fmaf(C, C, S * S);  // identical psd expression
}

// ---------------------------------------------------------------------------
// Kernel 2 (round 8): single-pass loss over precomputed psd[b,f].
//  - closed-form np.argmin (monotone grid, +-2 window, identical fp32 expr)
//  - online softmax (kept bit-identical to previous version), shuffle-combined
//  - fused mean via atomicAdd into out (zeroed by kernel 1)
// Loads are now 5 coalesced 4B floats per thread (was 25 strided 8B gathers).
// ---------------------------------------------------------------------------
__global__ __launch_bounds__(256) void loss_kernel(
    const float* __restrict__ psd,        // [B,NFREQ]
    const float* __restrict__ f_true,     // [B]
    const float* __restrict__ sampling_f,
    const float* __restrict__ f_range,
    float* __restrict__ out)              // [1]
{
    const int b    = blockIdx.x;
    const int tid  = threadIdx.x;
    const int wave = tid >> 6;
    const int lane = tid & 63;

    __shared__ float wm[4];
    __shared__ float wl[4];
    __shared__ float s_pidx;

    const float f_min = f_range[0];
    const float step  = sampling_f[0];
    const float delta = (f_min + step) - f_min;
    const float ft    = f_true[b];

    // closed-form argmin (np first-occurrence semantics)
    int iq = (int)((ft - f_min) / delta + 0.5f);
    int lo = iq - 2; if (lo < 0) lo = 0;
    int hi = iq + 2; if (hi > NFREQ - 1) hi = NFREQ - 1;
    int   idx   = lo;
    float bestd = fabsf((f_min + (float)lo * delta) - ft);
    for (int i = lo + 1; i <= hi; ++i) {
        float d = fabsf((f_min + (float)i * delta) - ft);
        if (d < bestd) { bestd = d; idx = i; }     // strict < : first occurrence
    }

    // one pass: online max/sumexp over the precomputed psd row
    float m = -INFINITY, l = 0.0f;
    for (int i = tid; i < NFREQ; i += 256) {
        float v = psd[b * NFREQ + i];
        if (i == idx) s_pidx = v;                  // exactly one thread
        float mn = fmaxf(m, v);
        l = l * __expf(m - mn) + __expf(v - mn);
        m = mn;
    }
    // wave combine (64 lanes)
    for (int off = 32; off > 0; off >>= 1) {
        float m2 = __shfl_down(m, off);
        float l2 = __shfl_down(l, off);
        float mn = fmaxf(m, m2);
        l = l * __expf(m - mn) + l2 * __expf(m2 - mn);
        m = mn;
    }
    if (lane == 0) { wm[wave] = m; wl[wave] = l; }
    __syncthreads();

    if (tid == 0) {
        float gm = wm[0], gl = wl[0];
#pragma unroll
        for (int w = 1; w < 4; ++w) {
            float mn = fmaxf(gm, wm[w]);
            gl = gl * __expf(gm - mn) + wl[w] * __expf(wm[w] - mn);
            gm = mn;
        }
        float sm  = __expf(s_pidx - gm) / gl;
        float per = -logf(sm + 1e-8f);
        atomicAdd(out, per * (1.0f / (float)BATCH));
    }
}

extern "C" void kernel_launch(void* const* d_in, const int* in_sizes, int n_in,
                              void* d_out, int out_size, void* d_ws, size_t ws_size,
                              hipStream_t stream) {
    const float* x          = (const float*)d_in[0];
    const float* f_true     = (const float*)d_in[1];
    const float* fs         = (const float*)d_in[2];
    // d_in[3] = deltas (unused)
    const float* sampling_f = (const float*)d_in[4];
    const float* f_range    = (const float*)d_in[5];

    float* psd = (float*)d_ws;             // [B*NFREQ] float = 320 KB

    dim3 g1(BATCH, FCHUNKS);               // 64 x 5 = 320 blocks x 4 waves
    goertzel_psd_kernel<<<g1, FBLK, 0, stream>>>(x, fs, sampling_f, f_range,
                                                 psd, (float*)d_out);
    loss_kernel<<<BATCH, 256, 0, stream>>>(psd, f_true, sampling_f, f_range,
                                           (float*)d_out);
}